// Round 5
// baseline (183.483 us; speedup 1.0000x reference)
//
#include <hip/hip_runtime.h>

// Layout constants for activation (32, 16, 224, 224) fp32
#define HW      224
#define PLANE   50176            // 224*224
#define NSTRIDE 802816           // 16*PLANE

// Persistent grid-stride scheme. Work-units (one unit = one block-iteration):
// A: ch 0..3   : 1568 units x 1024 consecutive float4 (4 per thread)
// B: ch 4..7   : 3136 units x 256 2x4-regions (1 per thread)
// C: ch 8..11  : 1568 units x 256 4x4-blocks (1 per thread)
// D: ch 12..15 : 3200 units, one 9-row LDS strip per unit (cooperative)
constexpr int A_UNITS = 1568;
constexpr int B_UNITS = 3136;
constexpr int C_UNITS = 1568;
constexpr int D_UNITS = 3200;
constexpr int U_AB    = A_UNITS;            // 1568
constexpr int U_ABC   = U_AB + B_UNITS;     // 4704
constexpr int U_ABCD  = U_ABC + C_UNITS;    // 6272
constexpr int U_TOTAL = U_ABCD + D_UNITS;   // 9472
constexpr int NB = 2048;                    // 8 blocks/CU -> 100% wave occupancy

__global__ __launch_bounds__(256) void blockrelu_kernel(
    const float* __restrict__ in, float* __restrict__ out) {
  __shared__ float tile[9][228];
  __shared__ float maskL[3][76];
  const int t = threadIdx.x;

  for (int u = blockIdx.x; u < U_TOTAL; u += NB) {
    if (u < U_AB) {
      // A: 1024 consecutive float4s; thread handles f0, f0+256, f0+512, f0+768
      const int f0 = u * 1024 + t;
      long off[4];
      float4 v[4];
      bool relu[4];
      #pragma unroll
      for (int k = 0; k < 4; ++k) {
        int f = f0 + k * 256;
        int n = f / PLANE;
        int r = f - n * PLANE;
        relu[k] = (r / 12544) >= 2;           // ch 2..3 -> elementwise ReLU
        off[k] = (long)n * NSTRIDE + (long)r * 4;
        v[k] = *(const float4*)(in + off[k]); // 4 independent loads in flight
      }
      #pragma unroll
      for (int k = 0; k < 4; ++k) {
        float4 w = v[k];
        if (relu[k]) {
          w.x = (w.x >= 0.f) ? w.x : 0.f;
          w.y = (w.y >= 0.f) ? w.y : 0.f;
          w.z = (w.z >= 0.f) ? w.z : 0.f;
          w.w = (w.w >= 0.f) ? w.w : 0.f;
        }
        *(float4*)(out + off[k]) = w;
      }
    } else if (u < U_ABC) {
      // B: one 2-row x 4-col region (two 2x2 blocks) per thread
      int it = (u - U_AB) * 256 + t;
      int n = it / 25088;
      int v2 = it - n * 25088;
      int c = 4 + v2 / 6272;
      int w2 = v2 % 6272;
      int brow = w2 / 56;
      int rcol = w2 - brow * 56;
      long base = (long)n * NSTRIDE + (long)c * PLANE + (long)(2 * brow) * HW + 4 * rcol;
      float4 a = *(const float4*)(in + base);
      float4 b = *(const float4*)(in + base + HW);
      float s0 = ((a.x + a.y) + b.x) + b.y;   // row-major order (bit-exact, R1)
      float s1 = ((a.z + a.w) + b.z) + b.w;
      if (s0 < 0.f) { a.x = 0.f; a.y = 0.f; b.x = 0.f; b.y = 0.f; }
      if (s1 < 0.f) { a.z = 0.f; a.w = 0.f; b.z = 0.f; b.w = 0.f; }
      *(float4*)(out + base) = a;
      *(float4*)(out + base + HW) = b;
    } else if (u < U_ABCD) {
      // C: one 4x4 block per thread
      int it = (u - U_ABC) * 256 + t;
      int n = it / 12544;
      int v2 = it - n * 12544;
      int c = 8 + v2 / 3136;
      int w2 = v2 % 3136;
      int by = w2 / 56;
      int bx = w2 - by * 56;
      long base = (long)n * NSTRIDE + (long)c * PLANE + (long)(4 * by) * HW + 4 * bx;
      float4 r0 = *(const float4*)(in + base);
      float4 r1 = *(const float4*)(in + base + HW);
      float4 r2 = *(const float4*)(in + base + 2 * HW);
      float4 r3 = *(const float4*)(in + base + 3 * HW);
      float s = r0.x; s += r0.y; s += r0.z; s += r0.w;
      s += r1.x; s += r1.y; s += r1.z; s += r1.w;
      s += r2.x; s += r2.y; s += r2.z; s += r2.w;
      s += r3.x; s += r3.y; s += r3.z; s += r3.w;
      if (s < 0.f) {
        r0 = make_float4(0.f, 0.f, 0.f, 0.f);
        r1 = r0; r2 = r0; r3 = r0;
      }
      *(float4*)(out + base) = r0;
      *(float4*)(out + base + HW) = r1;
      *(float4*)(out + base + 2 * HW) = r2;
      *(float4*)(out + base + 3 * HW) = r3;
    } else {
      // D: 3x3 blocks via one cooperative 9-row LDS strip (branch is
      // workgroup-uniform, so __syncthreads inside is safe)
      int wg = u - U_ABCD;          // 0..3199
      int p = wg / 25;              // plane 0..127
      int sg = wg - p * 25;         // strip-group 0..24
      int n = p >> 2;
      int c = 12 + (p & 3);
      int h0 = sg * 9;
      int rows = (224 - h0 >= 9) ? 9 : (224 - h0);   // 9, or 8 for sg==24
      long pbase = (long)n * NSTRIDE + (long)c * PLANE;

      __syncthreads();  // protect tile reuse from previous iteration
      for (int i = t; i < 9 * 228; i += 256) ((float*)tile)[i] = 0.f;
      __syncthreads();

      const int nvec = rows * 56;
      for (int idx = t; idx < nvec; idx += 256) {
        int r = idx / 56;
        int q = idx - r * 56;
        float4 v = *(const float4*)(in + pbase + (long)(h0 + r) * HW + q * 4);
        *(float4*)&tile[r][q * 4] = v;
      }
      __syncthreads();

      if (t < 225) {
        int br = t / 75;
        int bx = t - br * 75;
        int r0 = br * 3, cc0 = bx * 3;
        float s = 0.f;
        #pragma unroll
        for (int i = 0; i < 3; ++i)
          #pragma unroll
          for (int j = 0; j < 3; ++j)
            s += tile[r0 + i][cc0 + j];
        maskL[br][bx] = (s >= 0.f) ? 1.f : 0.f;
      }
      __syncthreads();

      for (int idx = t; idx < nvec; idx += 256) {
        int r = idx / 56;
        int q = idx - r * 56;
        int col = q * 4;
        float4 v = *(const float4*)&tile[r][col];
        int br = r / 3;
        v.x *= maskL[br][(col    ) / 3];
        v.y *= maskL[br][(col + 1) / 3];
        v.z *= maskL[br][(col + 2) / 3];
        v.w *= maskL[br][(col + 3) / 3];
        *(float4*)(out + pbase + (long)(h0 + r) * HW + col) = v;
      }
    }
  }
}

extern "C" void kernel_launch(void* const* d_in, const int* in_sizes, int n_in,
                              void* d_out, int out_size, void* d_ws, size_t ws_size,
                              hipStream_t stream) {
  const float* act = (const float*)d_in[0];
  float* out = (float*)d_out;
  blockrelu_kernel<<<NB, 256, 0, stream>>>(act, out);
}